// Round 3
// baseline (157.724 us; speedup 1.0000x reference)
//
#include <hip/hip_runtime.h>
#include <hip/hip_bf16.h>

#define T 512
#define C 256
#define D12 12
#define HID 32
#define BN_EPS 1e-5f
#define SCALE 0.0625f

typedef __attribute__((ext_vector_type(8))) short bf16x8;
typedef __attribute__((ext_vector_type(4))) float f32x4;

static __device__ __forceinline__ short f2bf(float f) {
    __hip_bfloat16 h = __float2bfloat16(f);
    return *reinterpret_cast<short*>(&h);
}

// ---------------- k1a: h1 = relu(BN1(r @ w1)) -> bf16 [B*T*T][32] ----------
// 4 rows per thread, no barriers in hot path, w1 (BN-folded) broadcast from LDS.
__global__ __launch_bounds__(256) void k1a_h1(
    const float* __restrict__ r,
    const float* __restrict__ w1, const float* __restrict__ b1,
    const float* __restrict__ g1, const float* __restrict__ be1,
    const float* __restrict__ m1, const float* __restrict__ v1,
    short* __restrict__ h1bf)
{
    __shared__ float w1sh[D12 * HID];
    __shared__ float C1sh[HID];
    const int tid = threadIdx.x;
    if (tid < HID) {
        float s1 = g1[tid] * rsqrtf(v1[tid] + BN_EPS);
        C1sh[tid] = (b1[tid] - m1[tid]) * s1 + be1[tid];
        for (int d = 0; d < D12; ++d)
            w1sh[d * HID + tid] = w1[d * HID + tid] * s1;
    }
    __syncthreads();

    const int row0 = blockIdx.x * 1024 + tid;   // rows row0 + 256*j, j=0..3
    float rv[4][12];
    #pragma unroll
    for (int j = 0; j < 4; ++j) {
        const float4* p = reinterpret_cast<const float4*>(r + (size_t)(row0 + 256 * j) * D12);
        float4 a = p[0], b = p[1], c = p[2];
        rv[j][0] = a.x; rv[j][1] = a.y; rv[j][2]  = a.z; rv[j][3]  = a.w;
        rv[j][4] = b.x; rv[j][5] = b.y; rv[j][6]  = b.z; rv[j][7]  = b.w;
        rv[j][8] = c.x; rv[j][9] = c.y; rv[j][10] = c.z; rv[j][11] = c.w;
    }

    for (int hb = 0; hb < 4; ++hb) {           // 8 h-columns per pass
        bf16x8 o[4];
        #pragma unroll
        for (int hh = 0; hh < 8; ++hh) {
            int h = hb * 8 + hh;
            float c0 = C1sh[h];
            float acc[4] = {c0, c0, c0, c0};
            #pragma unroll
            for (int d = 0; d < D12; ++d) {
                float w = w1sh[d * HID + h];
                #pragma unroll
                for (int j = 0; j < 4; ++j) acc[j] += rv[j][d] * w;
            }
            #pragma unroll
            for (int j = 0; j < 4; ++j) o[j][hh] = f2bf(fmaxf(acc[j], 0.f));
        }
        #pragma unroll
        for (int j = 0; j < 4; ++j)
            *reinterpret_cast<bf16x8*>(h1bf + (size_t)(row0 + 256 * j) * HID + hb * 8) = o[j];
    }
}

// ---------------- k1b: h2 col-max + bias add; A-frags direct from global ----
// one block per (b,s); wave w owns columns 64w..64w+63. No LDS in main loop.
__global__ __launch_bounds__(256) void k1b_l2max(
    const short* __restrict__ h1bf, const float* __restrict__ x,
    const float* __restrict__ w2, const float* __restrict__ b2,
    const float* __restrict__ g2, const float* __restrict__ be2,
    const float* __restrict__ m2, const float* __restrict__ v2,
    short* __restrict__ xbb)
{
    __shared__ float biassh[C];
    const int tid  = threadIdx.x;
    const int lane = tid & 63;
    const int wave = tid >> 6;
    const int quad = lane >> 4;
    const int mrow = lane & 15;
    const int blk  = blockIdx.x;   // b*T + s

    bf16x8 bfrag[4];
    float  c2r[4];
    #pragma unroll
    for (int ct = 0; ct < 4; ++ct) {
        int c = wave * 64 + ct * 16 + mrow;
        float s2 = g2[c] * rsqrtf(v2[c] + BN_EPS);
        c2r[ct] = (b2[c] - m2[c]) * s2 + be2[c];
        #pragma unroll
        for (int j = 0; j < 8; ++j)
            bfrag[ct][j] = f2bf(w2[(quad * 8 + j) * C + c] * s2);
    }

    const short* hbase = h1bf + (size_t)blk * T * HID;
    float maxv[4] = {-1e30f, -1e30f, -1e30f, -1e30f};
    #pragma unroll 4
    for (int rt = 0; rt < 32; ++rt) {
        bf16x8 af = *reinterpret_cast<const bf16x8*>(
            hbase + (size_t)(rt * 16 + mrow) * HID + quad * 8);
        #pragma unroll
        for (int ct = 0; ct < 4; ++ct) {
            f32x4 acc = {0.f, 0.f, 0.f, 0.f};
            acc = __builtin_amdgcn_mfma_f32_16x16x32_bf16(af, bfrag[ct], acc, 0, 0, 0);
            maxv[ct] = fmaxf(maxv[ct], fmaxf(fmaxf(acc[0], acc[1]), fmaxf(acc[2], acc[3])));
        }
    }
    // cross-quad max (same column, different row groups), then BN const + relu
    #pragma unroll
    for (int ct = 0; ct < 4; ++ct) {
        float m = maxv[ct];
        m = fmaxf(m, __shfl_xor(m, 16));
        m = fmaxf(m, __shfl_xor(m, 32));
        if (quad == 0) biassh[wave * 64 + ct * 16 + mrow] = fmaxf(m + c2r[ct], 0.f);
    }
    __syncthreads();
    xbb[(size_t)blk * C + tid] = f2bf(x[(size_t)blk * C + tid] + biassh[tid]);
}

// ---------------- k0: w_qkv [256][768] f32 -> wT [768][256] bf16 (tiled) ----
__global__ __launch_bounds__(256) void k0_transpose(
    const float* __restrict__ w, short* __restrict__ wT)
{
    __shared__ short tsh[64 * 66];
    const int tid = threadIdx.x;
    const int d0 = (blockIdx.x / 12) * 64;
    const int e0 = (blockIdx.x % 12) * 64;
    #pragma unroll
    for (int i = 0; i < 16; ++i) {
        int idx = i * 256 + tid;
        int di = idx >> 6, ej = idx & 63;
        tsh[di * 66 + ej] = f2bf(w[(size_t)(d0 + di) * 768 + e0 + ej]);
    }
    __syncthreads();
    #pragma unroll
    for (int i = 0; i < 16; ++i) {
        int idx = i * 256 + tid;
        int ei = idx >> 6, dj = idx & 63;
        wT[(size_t)(e0 + ei) * 256 + d0 + dj] = tsh[dj * 66 + ei];
    }
}

// ---------------- k2: qkv_bf = xb @ w_qkv via MFMA (bf16 out, q pre-scaled) --
__global__ __launch_bounds__(256) void k2_qkv(
    const short* __restrict__ xbb, const short* __restrict__ wT,
    short* __restrict__ qbf)
{
    const int tid  = threadIdx.x;
    const int lane = tid & 63;
    const int wave = tid >> 6;
    const int quad = lane >> 4;
    const int mrow = lane & 15;
    const int rb = blockIdx.x / 12;
    const int cb = blockIdx.x % 12;
    const int row0 = rb * 64 + wave * 16;
    const int col0 = cb * 64;
    const float osc = (cb < 4) ? SCALE : 1.0f;

    f32x4 acc[4];
    #pragma unroll
    for (int ct = 0; ct < 4; ++ct) acc[ct] = (f32x4){0.f, 0.f, 0.f, 0.f};

    for (int ks = 0; ks < 8; ++ks) {
        bf16x8 afrag = *reinterpret_cast<const bf16x8*>(
            &xbb[(size_t)(row0 + mrow) * 256 + ks * 32 + quad * 8]);
        #pragma unroll
        for (int ct = 0; ct < 4; ++ct) {
            bf16x8 bfrag = *reinterpret_cast<const bf16x8*>(
                &wT[(size_t)(col0 + ct * 16 + mrow) * 256 + ks * 32 + quad * 8]);
            acc[ct] = __builtin_amdgcn_mfma_f32_16x16x32_bf16(afrag, bfrag, acc[ct], 0, 0, 0);
        }
    }
    #pragma unroll
    for (int ct = 0; ct < 4; ++ct)
        #pragma unroll
        for (int rg = 0; rg < 4; ++rg)
            qbf[(size_t)(row0 + quad * 4 + rg) * 768 + col0 + ct * 16 + mrow] =
                f2bf(acc[ct][rg] * osc);
}

// ---------------- k2b: V part of qkv_bf -> vT[b][d][s] bf16 (tiled) --------
__global__ __launch_bounds__(256) void k2b_vtrans(
    const short* __restrict__ qbf, short* __restrict__ vT)
{
    __shared__ short tsh[64 * 66];
    const int tid = threadIdx.x;
    const int r0 = (blockIdx.x >> 2) * 64;
    const int c0 = (blockIdx.x & 3) * 64;
    #pragma unroll
    for (int i = 0; i < 16; ++i) {
        int idx = i * 256 + tid;
        int ri = idx >> 6, cj = idx & 63;
        tsh[ri * 66 + cj] = qbf[(size_t)(r0 + ri) * 768 + 512 + c0 + cj];
    }
    __syncthreads();
    const int b  = r0 >> 9;
    const int rb = r0 & 511;
    #pragma unroll
    for (int i = 0; i < 16; ++i) {
        int idx = i * 256 + tid;
        int ci = idx >> 6, rj = idx & 63;
        vT[((size_t)(b * 256 + c0 + ci)) * 512 + rb + rj] = tsh[rj * 66 + ci];
    }
}

// ---------------- k3a: flash attention partials via MFMA -------------------
__global__ __launch_bounds__(256) void k3a_attn(
    const short* __restrict__ qbf, const short* __restrict__ vT,
    float* __restrict__ po, float2* __restrict__ stats)
{
    __shared__ float msh[4][16];
    __shared__ float lsh[4][16];
    __shared__ short psh[16 * 136];
    const int tid  = threadIdx.x;
    const int lane = tid & 63;
    const int wave = tid >> 6;
    const int quad = lane >> 4;
    const int mrow = lane & 15;
    const int qt = blockIdx.x >> 2;
    const int sc = blockIdx.x & 3;
    const int b  = qt >> 5;
    const int row0  = qt * 16;
    const int srow0 = b * 512 + sc * 128;

    bf16x8 qf[8];
    {
        const short* qrow = qbf + (size_t)(row0 + mrow) * 768;
        #pragma unroll
        for (int ks = 0; ks < 8; ++ks)
            qf[ks] = *reinterpret_cast<const bf16x8*>(qrow + ks * 32 + quad * 8);
    }

    f32x4 S[2];
    #pragma unroll
    for (int st = 0; st < 2; ++st) {
        f32x4 acc = {0.f, 0.f, 0.f, 0.f};
        const short* krow = qbf + (size_t)(srow0 + wave * 32 + st * 16 + mrow) * 768 + 256;
        #pragma unroll
        for (int ks = 0; ks < 8; ++ks) {
            bf16x8 kf = *reinterpret_cast<const bf16x8*>(krow + ks * 32 + quad * 8);
            acc = __builtin_amdgcn_mfma_f32_16x16x32_bf16(qf[ks], kf, acc, 0, 0, 0);
        }
        S[st] = acc;
    }

    float mx[4];
    #pragma unroll
    for (int rg = 0; rg < 4; ++rg) mx[rg] = fmaxf(S[0][rg], S[1][rg]);
    #pragma unroll
    for (int off = 1; off < 16; off <<= 1)
        #pragma unroll
        for (int rg = 0; rg < 4; ++rg) mx[rg] = fmaxf(mx[rg], __shfl_xor(mx[rg], off));
    if (mrow == 0)
        #pragma unroll
        for (int rg = 0; rg < 4; ++rg) msh[wave][quad * 4 + rg] = mx[rg];
    __syncthreads();

    float M[4], sm[4];
    #pragma unroll
    for (int rg = 0; rg < 4; ++rg) {
        int m = quad * 4 + rg;
        M[rg] = fmaxf(fmaxf(msh[0][m], msh[1][m]), fmaxf(msh[2][m], msh[3][m]));
    }
    float ex[2][4];
    #pragma unroll
    for (int st = 0; st < 2; ++st)
        #pragma unroll
        for (int rg = 0; rg < 4; ++rg) ex[st][rg] = __expf(S[st][rg] - M[rg]);
    #pragma unroll
    for (int rg = 0; rg < 4; ++rg) sm[rg] = ex[0][rg] + ex[1][rg];
    #pragma unroll
    for (int off = 1; off < 16; off <<= 1)
        #pragma unroll
        for (int rg = 0; rg < 4; ++rg) sm[rg] += __shfl_xor(sm[rg], off);
    if (mrow == 0)
        #pragma unroll
        for (int rg = 0; rg < 4; ++rg) lsh[wave][quad * 4 + rg] = sm[rg];
    #pragma unroll
    for (int st = 0; st < 2; ++st)
        #pragma unroll
        for (int rg = 0; rg < 4; ++rg)
            psh[(quad * 4 + rg) * 136 + wave * 32 + st * 16 + mrow] = f2bf(ex[st][rg]);
    __syncthreads();

    if (wave == 0 && mrow == 0) {
        #pragma unroll
        for (int rg = 0; rg < 4; ++rg) {
            int m = quad * 4 + rg;
            float l = lsh[0][m] + lsh[1][m] + lsh[2][m] + lsh[3][m];
            stats[blockIdx.x * 16 + m] = make_float2(M[rg], l);
        }
    }

    const short* vbase = vT + (size_t)b * 256 * 512;
    f32x4 o[4];
    #pragma unroll
    for (int i = 0; i < 4; ++i) o[i] = (f32x4){0.f, 0.f, 0.f, 0.f};
    #pragma unroll
    for (int ks = 0; ks < 4; ++ks) {
        bf16x8 pf = *reinterpret_cast<const bf16x8*>(&psh[mrow * 136 + ks * 32 + quad * 8]);
        #pragma unroll
        for (int i = 0; i < 4; ++i) {
            int d0 = (wave * 4 + i) * 16;
            bf16x8 vf = *reinterpret_cast<const bf16x8*>(
                vbase + (size_t)(d0 + mrow) * 512 + sc * 128 + ks * 32 + quad * 8);
            o[i] = __builtin_amdgcn_mfma_f32_16x16x32_bf16(pf, vf, o[i], 0, 0, 0);
        }
    }
    #pragma unroll
    for (int i = 0; i < 4; ++i)
        #pragma unroll
        for (int rg = 0; rg < 4; ++rg)
            po[((size_t)blockIdx.x * 16 + quad * 4 + rg) * 256 + (wave * 4 + i) * 16 + mrow] =
                o[i][rg];
}

// ---------------- k3b: combine 4 chunk partials per row --------------------
__global__ __launch_bounds__(256) void k3b_combine(
    const float* __restrict__ po, const float2* __restrict__ stats,
    float* __restrict__ out)
{
    const int row = blockIdx.x;
    const int qt = row >> 4, m = row & 15;
    const int c = threadIdx.x;
    float2 s0 = stats[(qt * 4 + 0) * 16 + m];
    float2 s1 = stats[(qt * 4 + 1) * 16 + m];
    float2 s2 = stats[(qt * 4 + 2) * 16 + m];
    float2 s3 = stats[(qt * 4 + 3) * 16 + m];
    float M = fmaxf(fmaxf(s0.x, s1.x), fmaxf(s2.x, s3.x));
    float a0 = __expf(s0.x - M), a1 = __expf(s1.x - M);
    float a2 = __expf(s2.x - M), a3 = __expf(s3.x - M);
    float inv = 1.f / (a0 * s0.y + a1 * s1.y + a2 * s2.y + a3 * s3.y);
    float acc = a0 * po[((size_t)(qt * 4 + 0) * 16 + m) * 256 + c]
              + a1 * po[((size_t)(qt * 4 + 1) * 16 + m) * 256 + c]
              + a2 * po[((size_t)(qt * 4 + 2) * 16 + m) * 256 + c]
              + a3 * po[((size_t)(qt * 4 + 3) * 16 + m) * 256 + c];
    out[(size_t)row * 256 + c] = acc * inv;
}

extern "C" void kernel_launch(void* const* d_in, const int* in_sizes, int n_in,
                              void* d_out, int out_size, void* d_ws, size_t ws_size,
                              hipStream_t stream) {
    const float* x    = (const float*)d_in[0];
    const float* r    = (const float*)d_in[1];
    const float* w1   = (const float*)d_in[2];
    const float* b1   = (const float*)d_in[3];
    const float* g1   = (const float*)d_in[4];
    const float* be1  = (const float*)d_in[5];
    const float* m1   = (const float*)d_in[6];
    const float* v1   = (const float*)d_in[7];
    const float* w2   = (const float*)d_in[8];
    const float* b2   = (const float*)d_in[9];
    const float* g2   = (const float*)d_in[10];
    const float* be2  = (const float*)d_in[11];
    const float* m2   = (const float*)d_in[12];
    const float* v2   = (const float*)d_in[13];
    const float* wqkv = (const float*)d_in[14];
    float* out = (float*)d_out;

    // ws layout (bytes):
    //   qbf   [1024*768] bf16     @ 0
    //   vT    [2*256*512] bf16    @ 1,572,864
    //   xbb   [1024*256] bf16     @ 2,097,152
    //   wT    [768*256] bf16      @ 2,621,440
    //   po    [256*16*256] f32    @ 3,014,656
    //   stats [256*16] float2     @ 7,208,960
    //   h1bf  [524288*32] bf16    @ 8,388,608  (33,554,432)
    char* ws = (char*)d_ws;
    short*  qbf   = (short*)(ws);
    short*  vT    = (short*)(ws + 1572864);
    short*  xbb   = (short*)(ws + 2097152);
    short*  wT    = (short*)(ws + 2621440);
    float*  po    = (float*)(ws + 3014656);
    float2* stats = (float2*)(ws + 7208960);
    short*  h1bf  = (short*)(ws + 8388608);

    k0_transpose<<<48, 256, 0, stream>>>(wqkv, wT);
    k1a_h1<<<512, 256, 0, stream>>>(r, w1, b1, g1, be1, m1, v1, h1bf);
    k1b_l2max<<<1024, 256, 0, stream>>>(h1bf, x, w2, b2, g2, be2, m2, v2, xbb);
    k2_qkv<<<192, 256, 0, stream>>>(xbb, wT, qbf);
    k2b_vtrans<<<64, 256, 0, stream>>>(qbf, vT);
    k3a_attn<<<256, 256, 0, stream>>>(qbf, vT, po, stats);
    k3b_combine<<<1024, 256, 0, stream>>>(po, stats, out);
}

// Round 5
// 143.403 us; speedup vs baseline: 1.0999x; 1.0999x over previous
//
#include <hip/hip_runtime.h>
#include <hip/hip_bf16.h>

#define T 512
#define C 256
#define D12 12
#define HID 32
#define BN_EPS 1e-5f
#define SCALE 0.0625f

typedef __attribute__((ext_vector_type(8))) short bf16x8;
typedef __attribute__((ext_vector_type(4))) float f32x4;

static __device__ __forceinline__ short f2bf(float f) {
    __hip_bfloat16 h = __float2bfloat16(f);
    return *reinterpret_cast<short*>(&h);
}

// ---------------- k1w: fused TPR MLP + col-max + bias, wave-private LDS -----
// 1 block per (b,s); wave w owns t-rows w*128..w*128+127 with its own LDS
// strips (no __syncthreads in hot loop — within-wave DS ordering only).
// Layer1: A = r-tile rows (LDS), B = w1'(BN-folded) regs -> D[t][h] -> LDS
// (the LDS round-trip is the verified C->A layout transform from round 2).
// Layer2: A = h1 rows (LDS), B = w2'(BN-folded) regs, raw-max epilogue.
__global__ __launch_bounds__(256) void k1w_mlp_bias(
    const float* __restrict__ x, const float* __restrict__ r,
    const float* __restrict__ w1, const float* __restrict__ b1,
    const float* __restrict__ g1, const float* __restrict__ be1,
    const float* __restrict__ m1, const float* __restrict__ v1,
    const float* __restrict__ w2, const float* __restrict__ b2,
    const float* __restrict__ g2, const float* __restrict__ be2,
    const float* __restrict__ m2, const float* __restrict__ v2,
    short* __restrict__ xbb)
{
    __shared__ short rp[4][16 * 40];   // per-wave r tile, k padded 12->40(=0)
    __shared__ short h1p[4][16 * 40];  // per-wave h1 tile [t][h], stride 40
    __shared__ float bsh[4][C];
    const int tid  = threadIdx.x;
    const int lane = tid & 63;
    const int wave = tid >> 6;
    const int quad = lane >> 4;
    const int mrow = lane & 15;
    const int blk  = blockIdx.x;

    short* rw = &rp[wave][0];
    short* hw = &h1p[wave][0];

    // zero the k-pad region of rw once (staging only writes k<12)
    #pragma unroll
    for (int i = 0; i < 7; ++i) {
        int idx = i * 64 + lane;          // < 448 = 16*28
        int row = idx / 28, d = 12 + idx % 28;
        rw[row * 40 + d] = 0;
    }

    // layer1 B-frags: B[n=h][k] = w1[k][h]*s1[h] (k<12 else 0); init const per h
    bf16x8 b1f[2];
    float  c1i[2];
    #pragma unroll
    for (int nt = 0; nt < 2; ++nt) {
        int h = nt * 16 + mrow;
        float s1 = g1[h] * rsqrtf(v1[h] + BN_EPS);
        c1i[nt] = (b1[h] - m1[h]) * s1 + be1[h];
        #pragma unroll
        for (int j = 0; j < 8; ++j) {
            int k = quad * 8 + j;
            b1f[nt][j] = (k < D12) ? f2bf(w1[k * HID + h] * s1) : (short)0;
        }
    }

    // layer2 B-frags: B[n=c][k=h] = w2[h][c]*s2[c], 16 col-tiles (all 256 cols)
    bf16x8 b2f[16];
    #pragma unroll
    for (int ct = 0; ct < 16; ++ct) {
        int c = ct * 16 + mrow;
        float s2 = g2[c] * rsqrtf(v2[c] + BN_EPS);
        #pragma unroll
        for (int j = 0; j < 8; ++j)
            b2f[ct][j] = f2bf(w2[(quad * 8 + j) * C + c] * s2);
    }

    const float* rb = r + ((size_t)blk * T + wave * 128) * D12;
    float maxv[16];
    #pragma unroll
    for (int ct = 0; ct < 16; ++ct) maxv[ct] = -1e30f;

    for (int tile = 0; tile < 8; ++tile) {
        // stage 16 rows of r (192 floats, coalesced) -> bf16 LDS
        #pragma unroll
        for (int i = 0; i < 3; ++i) {
            int idx = i * 64 + lane;
            int row = idx / 12, d = idx - row * 12;
            rw[row * 40 + d] = f2bf(rb[tile * 192 + idx]);
        }
        // layer1: A[m=t=mrow][k] from LDS, D[t'=quad*4+rg][h'=mrow] -> LDS
        {
            bf16x8 af = *reinterpret_cast<const bf16x8*>(&rw[mrow * 40 + quad * 8]);
            #pragma unroll
            for (int nt = 0; nt < 2; ++nt) {
                f32x4 a = {c1i[nt], c1i[nt], c1i[nt], c1i[nt]};
                a = __builtin_amdgcn_mfma_f32_16x16x32_bf16(af, b1f[nt], a, 0, 0, 0);
                #pragma unroll
                for (int rg = 0; rg < 4; ++rg)
                    hw[(quad * 4 + rg) * 40 + nt * 16 + mrow] = f2bf(fmaxf(a[rg], 0.f));
            }
        }
        // layer2: A[m=t=mrow][k=h] from LDS, 16 col-tiles, raw-max epilogue
        {
            bf16x8 a2 = *reinterpret_cast<const bf16x8*>(&hw[mrow * 40 + quad * 8]);
            #pragma unroll
            for (int ct = 0; ct < 16; ++ct) {
                f32x4 acc = {0.f, 0.f, 0.f, 0.f};
                acc = __builtin_amdgcn_mfma_f32_16x16x32_bf16(a2, b2f[ct], acc, 0, 0, 0);
                maxv[ct] = fmaxf(maxv[ct],
                                 fmaxf(fmaxf(acc[0], acc[1]), fmaxf(acc[2], acc[3])));
            }
        }
    }

    // cross-quad reduce (t-rows spread over quads), per-wave partial to LDS
    #pragma unroll
    for (int ct = 0; ct < 16; ++ct) {
        float m = maxv[ct];
        m = fmaxf(m, __shfl_xor(m, 16));
        m = fmaxf(m, __shfl_xor(m, 32));
        if (quad == 0) bsh[wave][ct * 16 + mrow] = m;
    }
    __syncthreads();

    float mraw = fmaxf(fmaxf(bsh[0][tid], bsh[1][tid]),
                       fmaxf(bsh[2][tid], bsh[3][tid]));
    float s2 = g2[tid] * rsqrtf(v2[tid] + BN_EPS);
    float c2 = (b2[tid] - m2[tid]) * s2 + be2[tid];
    float bias = fmaxf(mraw + c2, 0.f);
    xbb[(size_t)blk * C + tid] = f2bf(x[(size_t)blk * C + tid] + bias);
}

// ---------------- k0: w_qkv [256][768] f32 -> wT [768][256] bf16 (tiled) ----
__global__ __launch_bounds__(256) void k0_transpose(
    const float* __restrict__ w, short* __restrict__ wT)
{
    __shared__ short tsh[64 * 66];
    const int tid = threadIdx.x;
    const int d0 = (blockIdx.x / 12) * 64;
    const int e0 = (blockIdx.x % 12) * 64;
    #pragma unroll
    for (int i = 0; i < 16; ++i) {
        int idx = i * 256 + tid;
        int di = idx >> 6, ej = idx & 63;
        tsh[di * 66 + ej] = f2bf(w[(size_t)(d0 + di) * 768 + e0 + ej]);
    }
    __syncthreads();
    #pragma unroll
    for (int i = 0; i < 16; ++i) {
        int idx = i * 256 + tid;
        int ei = idx >> 6, dj = idx & 63;
        wT[(size_t)(e0 + ei) * 256 + d0 + dj] = tsh[dj * 66 + ei];
    }
}

// ---------------- k2: qkv_bf = xb @ w_qkv via MFMA (bf16 out, q pre-scaled) --
__global__ __launch_bounds__(256) void k2_qkv(
    const short* __restrict__ xbb, const short* __restrict__ wT,
    short* __restrict__ qbf)
{
    const int tid  = threadIdx.x;
    const int lane = tid & 63;
    const int wave = tid >> 6;
    const int quad = lane >> 4;
    const int mrow = lane & 15;
    const int rb = blockIdx.x / 12;
    const int cb = blockIdx.x % 12;
    const int row0 = rb * 64 + wave * 16;
    const int col0 = cb * 64;
    const float osc = (cb < 4) ? SCALE : 1.0f;

    f32x4 acc[4];
    #pragma unroll
    for (int ct = 0; ct < 4; ++ct) acc[ct] = (f32x4){0.f, 0.f, 0.f, 0.f};

    for (int ks = 0; ks < 8; ++ks) {
        bf16x8 afrag = *reinterpret_cast<const bf16x8*>(
            &xbb[(size_t)(row0 + mrow) * 256 + ks * 32 + quad * 8]);
        #pragma unroll
        for (int ct = 0; ct < 4; ++ct) {
            bf16x8 bfrag = *reinterpret_cast<const bf16x8*>(
                &wT[(size_t)(col0 + ct * 16 + mrow) * 256 + ks * 32 + quad * 8]);
            acc[ct] = __builtin_amdgcn_mfma_f32_16x16x32_bf16(afrag, bfrag, acc[ct], 0, 0, 0);
        }
    }
    #pragma unroll
    for (int ct = 0; ct < 4; ++ct)
        #pragma unroll
        for (int rg = 0; rg < 4; ++rg)
            qbf[(size_t)(row0 + quad * 4 + rg) * 768 + col0 + ct * 16 + mrow] =
                f2bf(acc[ct][rg] * osc);
}

// ---------------- k2b: V part of qkv_bf -> vT[b][d][s] bf16 (tiled) --------
__global__ __launch_bounds__(256) void k2b_vtrans(
    const short* __restrict__ qbf, short* __restrict__ vT)
{
    __shared__ short tsh[64 * 66];
    const int tid = threadIdx.x;
    const int r0 = (blockIdx.x >> 2) * 64;
    const int c0 = (blockIdx.x & 3) * 64;
    #pragma unroll
    for (int i = 0; i < 16; ++i) {
        int idx = i * 256 + tid;
        int ri = idx >> 6, cj = idx & 63;
        tsh[ri * 66 + cj] = qbf[(size_t)(r0 + ri) * 768 + 512 + c0 + cj];
    }
    __syncthreads();
    const int b  = r0 >> 9;
    const int rb = r0 & 511;
    #pragma unroll
    for (int i = 0; i < 16; ++i) {
        int idx = i * 256 + tid;
        int ci = idx >> 6, rj = idx & 63;
        vT[((size_t)(b * 256 + c0 + ci)) * 512 + rb + rj] = tsh[rj * 66 + ci];
    }
}

// ---------------- k3a: flash attention partials via MFMA -------------------
__global__ __launch_bounds__(256) void k3a_attn(
    const short* __restrict__ qbf, const short* __restrict__ vT,
    float* __restrict__ po, float2* __restrict__ stats)
{
    __shared__ float msh[4][16];
    __shared__ float lsh[4][16];
    __shared__ short psh[16 * 136];
    const int tid  = threadIdx.x;
    const int lane = tid & 63;
    const int wave = tid >> 6;
    const int quad = lane >> 4;
    const int mrow = lane & 15;
    const int qt = blockIdx.x >> 2;
    const int sc = blockIdx.x & 3;
    const int b  = qt >> 5;
    const int row0  = qt * 16;
    const int srow0 = b * 512 + sc * 128;

    bf16x8 qf[8];
    {
        const short* qrow = qbf + (size_t)(row0 + mrow) * 768;
        #pragma unroll
        for (int ks = 0; ks < 8; ++ks)
            qf[ks] = *reinterpret_cast<const bf16x8*>(qrow + ks * 32 + quad * 8);
    }

    f32x4 S[2];
    #pragma unroll
    for (int st = 0; st < 2; ++st) {
        f32x4 acc = {0.f, 0.f, 0.f, 0.f};
        const short* krow = qbf + (size_t)(srow0 + wave * 32 + st * 16 + mrow) * 768 + 256;
        #pragma unroll
        for (int ks = 0; ks < 8; ++ks) {
            bf16x8 kf = *reinterpret_cast<const bf16x8*>(krow + ks * 32 + quad * 8);
            acc = __builtin_amdgcn_mfma_f32_16x16x32_bf16(qf[ks], kf, acc, 0, 0, 0);
        }
        S[st] = acc;
    }

    float mx[4];
    #pragma unroll
    for (int rg = 0; rg < 4; ++rg) mx[rg] = fmaxf(S[0][rg], S[1][rg]);
    #pragma unroll
    for (int off = 1; off < 16; off <<= 1)
        #pragma unroll
        for (int rg = 0; rg < 4; ++rg) mx[rg] = fmaxf(mx[rg], __shfl_xor(mx[rg], off));
    if (mrow == 0)
        #pragma unroll
        for (int rg = 0; rg < 4; ++rg) msh[wave][quad * 4 + rg] = mx[rg];
    __syncthreads();

    float M[4], sm[4];
    #pragma unroll
    for (int rg = 0; rg < 4; ++rg) {
        int m = quad * 4 + rg;
        M[rg] = fmaxf(fmaxf(msh[0][m], msh[1][m]), fmaxf(msh[2][m], msh[3][m]));
    }
    float ex[2][4];
    #pragma unroll
    for (int st = 0; st < 2; ++st)
        #pragma unroll
        for (int rg = 0; rg < 4; ++rg) ex[st][rg] = __expf(S[st][rg] - M[rg]);
    #pragma unroll
    for (int rg = 0; rg < 4; ++rg) sm[rg] = ex[0][rg] + ex[1][rg];
    #pragma unroll
    for (int off = 1; off < 16; off <<= 1)
        #pragma unroll
        for (int rg = 0; rg < 4; ++rg) sm[rg] += __shfl_xor(sm[rg], off);
    if (mrow == 0)
        #pragma unroll
        for (int rg = 0; rg < 4; ++rg) lsh[wave][quad * 4 + rg] = sm[rg];
    #pragma unroll
    for (int st = 0; st < 2; ++st)
        #pragma unroll
        for (int rg = 0; rg < 4; ++rg)
            psh[(quad * 4 + rg) * 136 + wave * 32 + st * 16 + mrow] = f2bf(ex[st][rg]);
    __syncthreads();

    if (wave == 0 && mrow == 0) {
        #pragma unroll
        for (int rg = 0; rg < 4; ++rg) {
            int m = quad * 4 + rg;
            float l = lsh[0][m] + lsh[1][m] + lsh[2][m] + lsh[3][m];
            stats[blockIdx.x * 16 + m] = make_float2(M[rg], l);
        }
    }

    const short* vbase = vT + (size_t)b * 256 * 512;
    f32x4 o[4];
    #pragma unroll
    for (int i = 0; i < 4; ++i) o[i] = (f32x4){0.f, 0.f, 0.f, 0.f};
    #pragma unroll
    for (int ks = 0; ks < 4; ++ks) {
        bf16x8 pf = *reinterpret_cast<const bf16x8*>(&psh[mrow * 136 + ks * 32 + quad * 8]);
        #pragma unroll
        for (int i = 0; i < 4; ++i) {
            int d0 = (wave * 4 + i) * 16;
            bf16x8 vf = *reinterpret_cast<const bf16x8*>(
                vbase + (size_t)(d0 + mrow) * 512 + sc * 128 + ks * 32 + quad * 8);
            o[i] = __builtin_amdgcn_mfma_f32_16x16x32_bf16(pf, vf, o[i], 0, 0, 0);
        }
    }
    #pragma unroll
    for (int i = 0; i < 4; ++i)
        #pragma unroll
        for (int rg = 0; rg < 4; ++rg)
            po[((size_t)blockIdx.x * 16 + quad * 4 + rg) * 256 + (wave * 4 + i) * 16 + mrow] =
                o[i][rg];
}

// ---------------- k3b: combine 4 chunk partials per row --------------------
__global__ __launch_bounds__(256) void k3b_combine(
    const float* __restrict__ po, const float2* __restrict__ stats,
    float* __restrict__ out)
{
    const int row = blockIdx.x;
    const int qt = row >> 4, m = row & 15;
    const int c = threadIdx.x;
    float2 s0 = stats[(qt * 4 + 0) * 16 + m];
    float2 s1 = stats[(qt * 4 + 1) * 16 + m];
    float2 s2 = stats[(qt * 4 + 2) * 16 + m];
    float2 s3 = stats[(qt * 4 + 3) * 16 + m];
    float M = fmaxf(fmaxf(s0.x, s1.x), fmaxf(s2.x, s3.x));
    float a0 = __expf(s0.x - M), a1 = __expf(s1.x - M);
    float a2 = __expf(s2.x - M), a3 = __expf(s3.x - M);
    float inv = 1.f / (a0 * s0.y + a1 * s1.y + a2 * s2.y + a3 * s3.y);
    float acc = a0 * po[((size_t)(qt * 4 + 0) * 16 + m) * 256 + c]
              + a1 * po[((size_t)(qt * 4 + 1) * 16 + m) * 256 + c]
              + a2 * po[((size_t)(qt * 4 + 2) * 16 + m) * 256 + c]
              + a3 * po[((size_t)(qt * 4 + 3) * 16 + m) * 256 + c];
    out[(size_t)row * 256 + c] = acc * inv;
}

extern "C" void kernel_launch(void* const* d_in, const int* in_sizes, int n_in,
                              void* d_out, int out_size, void* d_ws, size_t ws_size,
                              hipStream_t stream) {
    const float* x    = (const float*)d_in[0];
    const float* r    = (const float*)d_in[1];
    const float* w1   = (const float*)d_in[2];
    const float* b1   = (const float*)d_in[3];
    const float* g1   = (const float*)d_in[4];
    const float* be1  = (const float*)d_in[5];
    const float* m1   = (const float*)d_in[6];
    const float* v1   = (const float*)d_in[7];
    const float* w2   = (const float*)d_in[8];
    const float* b2   = (const float*)d_in[9];
    const float* g2   = (const float*)d_in[10];
    const float* be2  = (const float*)d_in[11];
    const float* m2   = (const float*)d_in[12];
    const float* v2   = (const float*)d_in[13];
    const float* wqkv = (const float*)d_in[14];
    float* out = (float*)d_out;

    // ws layout (bytes):
    //   qbf   [1024*768] bf16  @ 0
    //   vT    [2*256*512] bf16 @ 1,572,864
    //   xbb   [1024*256] bf16  @ 2,097,152
    //   wT    [768*256] bf16   @ 2,621,440
    //   po    [256*16*256] f32 @ 3,014,656
    //   stats [256*16] float2  @ 7,208,960
    char* ws = (char*)d_ws;
    short*  qbf   = (short*)(ws);
    short*  vT    = (short*)(ws + 1572864);
    short*  xbb   = (short*)(ws + 2097152);
    short*  wT    = (short*)(ws + 2621440);
    float*  po    = (float*)(ws + 3014656);
    float2* stats = (float2*)(ws + 7208960);

    k0_transpose<<<48, 256, 0, stream>>>(wqkv, wT);
    k1w_mlp_bias<<<1024, 256, 0, stream>>>(x, r, w1, b1, g1, be1, m1, v1,
                                           w2, b2, g2, be2, m2, v2, xbb);
    k2_qkv<<<192, 256, 0, stream>>>(xbb, wT, qbf);
    k2b_vtrans<<<64, 256, 0, stream>>>(qbf, vT);
    k3a_attn<<<256, 256, 0, stream>>>(qbf, vT, po, stats);
    k3b_combine<<<1024, 256, 0, stream>>>(po, stats, out);
}

// Round 6
// 129.400 us; speedup vs baseline: 1.2189x; 1.1082x over previous
//
#include <hip/hip_runtime.h>
#include <hip/hip_bf16.h>

#define T 512
#define C 256
#define D12 12
#define HID 32
#define BN_EPS 1e-5f
#define SCALE 0.0625f

typedef __attribute__((ext_vector_type(8))) short bf16x8;
typedef __attribute__((ext_vector_type(4))) float f32x4;

static __device__ __forceinline__ short f2bf(float f) {
    __hip_bfloat16 h = __float2bfloat16(f);
    return *reinterpret_cast<short*>(&h);
}

// ---- k1m: fused TPR MLP + col-max + bias (R2-proven) + w_qkv transpose ----
// blocks 0..1023: one per (b,s), exact round-2 k1_mlp_bias.
// blocks 1024..1071: w_qkv [256][768] f32 -> wT [768][256] bf16 (tiled).
__global__ __launch_bounds__(256) void k1m_mlp_bias(
    const float* __restrict__ x, const float* __restrict__ r,
    const float* __restrict__ w1, const float* __restrict__ b1,
    const float* __restrict__ g1, const float* __restrict__ be1,
    const float* __restrict__ m1, const float* __restrict__ v1,
    const float* __restrict__ w2, const float* __restrict__ b2,
    const float* __restrict__ g2, const float* __restrict__ be2,
    const float* __restrict__ m2, const float* __restrict__ v2,
    const float* __restrict__ wqkv,
    short* __restrict__ xbb, short* __restrict__ wT)
{
    __shared__ float s1sh[HID];
    __shared__ float C1sh[HID];
    __shared__ short w1t[32 * 32];
    __shared__ short rshbf[64 * 40];
    __shared__ short h1sh[64 * 40];
    __shared__ float biassh[C];
    __shared__ short tsh[64 * 66];

    const int tid  = threadIdx.x;
    const int blk  = blockIdx.x;

    if (blk >= 1024) {   // ---- transpose path (was k0) ----
        const int bid2 = blk - 1024;
        const int d0 = (bid2 / 12) * 64;
        const int e0 = (bid2 % 12) * 64;
        #pragma unroll
        for (int i = 0; i < 16; ++i) {
            int idx = i * 256 + tid;
            int di = idx >> 6, ej = idx & 63;
            tsh[di * 66 + ej] = f2bf(wqkv[(size_t)(d0 + di) * 768 + e0 + ej]);
        }
        __syncthreads();
        #pragma unroll
        for (int i = 0; i < 16; ++i) {
            int idx = i * 256 + tid;
            int ei = idx >> 6, dj = idx & 63;
            wT[(size_t)(e0 + ei) * 256 + d0 + dj] = tsh[dj * 66 + ei];
        }
        return;
    }

    const int lane = tid & 63;
    const int wave = tid >> 6;
    const int quad = lane >> 4;
    const int mrow = lane & 15;

    if (tid < HID) {
        float s1 = g1[tid] * rsqrtf(v1[tid] + BN_EPS);
        s1sh[tid] = s1;
        C1sh[tid] = (b1[tid] - m1[tid]) * s1 + be1[tid];
    }
    __syncthreads();

    #pragma unroll
    for (int i = 0; i < 4; ++i) {
        int idx = i * 256 + tid;
        int h = idx >> 5, d = idx & 31;
        float v = (d < D12) ? w1[d * HID + h] * s1sh[h] : 0.f;
        w1t[h * 32 + d] = f2bf(v);
    }
    #pragma unroll
    for (int i = 0; i < 7; ++i) {
        int idx = i * 256 + tid;
        int row = idx / 28, d = 12 + idx % 28;
        rshbf[row * 40 + d] = 0;
    }

    bf16x8 bfrag[4];
    float  c2r[4];
    #pragma unroll
    for (int ct = 0; ct < 4; ++ct) {
        int c = wave * 64 + ct * 16 + mrow;
        float s2 = g2[c] * rsqrtf(v2[c] + BN_EPS);
        c2r[ct] = (b2[c] - m2[c]) * s2 + be2[c];
        #pragma unroll
        for (int j = 0; j < 8; ++j) {
            int k = quad * 8 + j;
            bfrag[ct][j] = f2bf(w2[k * C + c] * s2);
        }
    }
    __syncthreads();

    bf16x8 b1f[2];
    float  c1r[2];
    #pragma unroll
    for (int nt = 0; nt < 2; ++nt) {
        b1f[nt] = *reinterpret_cast<const bf16x8*>(&w1t[(nt * 16 + mrow) * 32 + quad * 8]);
        c1r[nt] = C1sh[nt * 16 + mrow];
    }

    const float* rbase = r + (size_t)blk * T * D12;
    float maxv[4] = {0.f, 0.f, 0.f, 0.f};

    for (int t0 = 0; t0 < T; t0 += 64) {
        #pragma unroll
        for (int i = 0; i < 3; ++i) {
            int idx = i * 256 + tid;
            int row = idx / 12, d = idx - row * 12;
            rshbf[row * 40 + d] = f2bf(rbase[t0 * D12 + idx]);
        }
        __syncthreads();
        {
            bf16x8 af = *reinterpret_cast<const bf16x8*>(
                &rshbf[(wave * 16 + mrow) * 40 + quad * 8]);
            #pragma unroll
            for (int nt = 0; nt < 2; ++nt) {
                f32x4 a = {c1r[nt], c1r[nt], c1r[nt], c1r[nt]};
                a = __builtin_amdgcn_mfma_f32_16x16x32_bf16(af, b1f[nt], a, 0, 0, 0);
                #pragma unroll
                for (int rg = 0; rg < 4; ++rg)
                    h1sh[(wave * 16 + quad * 4 + rg) * 40 + nt * 16 + mrow] =
                        f2bf(fmaxf(a[rg], 0.f));
            }
        }
        __syncthreads();
        #pragma unroll
        for (int rt = 0; rt < 4; ++rt) {
            bf16x8 a2 = *reinterpret_cast<const bf16x8*>(
                &h1sh[(rt * 16 + mrow) * 40 + quad * 8]);
            #pragma unroll
            for (int ct = 0; ct < 4; ++ct) {
                f32x4 acc = {c2r[ct], c2r[ct], c2r[ct], c2r[ct]};
                acc = __builtin_amdgcn_mfma_f32_16x16x32_bf16(a2, bfrag[ct], acc, 0, 0, 0);
                #pragma unroll
                for (int rg = 0; rg < 4; ++rg)
                    maxv[ct] = fmaxf(maxv[ct], acc[rg]);
            }
        }
        __syncthreads();
    }

    #pragma unroll
    for (int ct = 0; ct < 4; ++ct) {
        float m = maxv[ct];
        m = fmaxf(m, __shfl_xor(m, 16));
        m = fmaxf(m, __shfl_xor(m, 32));
        if (quad == 0) biassh[wave * 64 + ct * 16 + mrow] = m;
    }
    __syncthreads();
    xbb[(size_t)blk * C + tid] = f2bf(x[(size_t)blk * C + tid] + biassh[tid]);
}

// ---- k2m: qkv GEMM; q/k -> qbf (q pre-scaled); v-blocks -> vT via LDS -----
__global__ __launch_bounds__(256) void k2m_qkv(
    const short* __restrict__ xbb, const short* __restrict__ wT,
    short* __restrict__ qbf, short* __restrict__ vT)
{
    __shared__ short tsh[64 * 66];
    const int tid  = threadIdx.x;
    const int lane = tid & 63;
    const int wave = tid >> 6;
    const int quad = lane >> 4;
    const int mrow = lane & 15;
    const int rb = blockIdx.x / 12;
    const int cb = blockIdx.x % 12;
    const int row0 = rb * 64 + wave * 16;
    const int col0 = cb * 64;
    const float osc = (cb < 4) ? SCALE : 1.0f;

    f32x4 acc[4];
    #pragma unroll
    for (int ct = 0; ct < 4; ++ct) acc[ct] = (f32x4){0.f, 0.f, 0.f, 0.f};

    for (int ks = 0; ks < 8; ++ks) {
        bf16x8 afrag = *reinterpret_cast<const bf16x8*>(
            &xbb[(size_t)(row0 + mrow) * 256 + ks * 32 + quad * 8]);
        #pragma unroll
        for (int ct = 0; ct < 4; ++ct) {
            bf16x8 bfrag = *reinterpret_cast<const bf16x8*>(
                &wT[(size_t)(col0 + ct * 16 + mrow) * 256 + ks * 32 + quad * 8]);
            acc[ct] = __builtin_amdgcn_mfma_f32_16x16x32_bf16(afrag, bfrag, acc[ct], 0, 0, 0);
        }
    }

    if (cb < 8) {   // q, k: direct store to qbf
        #pragma unroll
        for (int ct = 0; ct < 4; ++ct)
            #pragma unroll
            for (int rg = 0; rg < 4; ++rg)
                qbf[(size_t)(row0 + quad * 4 + rg) * 768 + col0 + ct * 16 + mrow] =
                    f2bf(acc[ct][rg] * osc);
    } else {        // v: transpose 64x64 tile through LDS, store to vT[b][d][s]
        #pragma unroll
        for (int ct = 0; ct < 4; ++ct)
            #pragma unroll
            for (int rg = 0; rg < 4; ++rg)
                tsh[(wave * 16 + quad * 4 + rg) * 66 + ct * 16 + mrow] = f2bf(acc[ct][rg]);
        __syncthreads();
        const int b  = rb >> 3;
        const int s0 = (rb & 7) * 64;
        const int dg = (cb - 8) * 64;
        #pragma unroll
        for (int i = 0; i < 16; ++i) {
            int idx = i * 256 + tid;
            int ci = idx >> 6, rj = idx & 63;
            vT[((size_t)(b * 256 + dg + ci)) * 512 + s0 + rj] = tsh[rj * 66 + ci];
        }
    }
}

// ---------------- k3a: flash attention partials via MFMA -------------------
__global__ __launch_bounds__(256) void k3a_attn(
    const short* __restrict__ qbf, const short* __restrict__ vT,
    float* __restrict__ po, float2* __restrict__ stats)
{
    __shared__ float msh[4][16];
    __shared__ float lsh[4][16];
    __shared__ short psh[16 * 136];
    const int tid  = threadIdx.x;
    const int lane = tid & 63;
    const int wave = tid >> 6;
    const int quad = lane >> 4;
    const int mrow = lane & 15;
    const int qt = blockIdx.x >> 2;
    const int sc = blockIdx.x & 3;
    const int b  = qt >> 5;
    const int row0  = qt * 16;
    const int srow0 = b * 512 + sc * 128;

    bf16x8 qf[8];
    {
        const short* qrow = qbf + (size_t)(row0 + mrow) * 768;
        #pragma unroll
        for (int ks = 0; ks < 8; ++ks)
            qf[ks] = *reinterpret_cast<const bf16x8*>(qrow + ks * 32 + quad * 8);
    }

    f32x4 S[2];
    #pragma unroll
    for (int st = 0; st < 2; ++st) {
        f32x4 acc = {0.f, 0.f, 0.f, 0.f};
        const short* krow = qbf + (size_t)(srow0 + wave * 32 + st * 16 + mrow) * 768 + 256;
        #pragma unroll
        for (int ks = 0; ks < 8; ++ks) {
            bf16x8 kf = *reinterpret_cast<const bf16x8*>(krow + ks * 32 + quad * 8);
            acc = __builtin_amdgcn_mfma_f32_16x16x32_bf16(qf[ks], kf, acc, 0, 0, 0);
        }
        S[st] = acc;
    }

    float mx[4];
    #pragma unroll
    for (int rg = 0; rg < 4; ++rg) mx[rg] = fmaxf(S[0][rg], S[1][rg]);
    #pragma unroll
    for (int off = 1; off < 16; off <<= 1)
        #pragma unroll
        for (int rg = 0; rg < 4; ++rg) mx[rg] = fmaxf(mx[rg], __shfl_xor(mx[rg], off));
    if (mrow == 0)
        #pragma unroll
        for (int rg = 0; rg < 4; ++rg) msh[wave][quad * 4 + rg] = mx[rg];
    __syncthreads();

    float M[4], sm[4];
    #pragma unroll
    for (int rg = 0; rg < 4; ++rg) {
        int m = quad * 4 + rg;
        M[rg] = fmaxf(fmaxf(msh[0][m], msh[1][m]), fmaxf(msh[2][m], msh[3][m]));
    }
    float ex[2][4];
    #pragma unroll
    for (int st = 0; st < 2; ++st)
        #pragma unroll
        for (int rg = 0; rg < 4; ++rg) ex[st][rg] = __expf(S[st][rg] - M[rg]);
    #pragma unroll
    for (int rg = 0; rg < 4; ++rg) sm[rg] = ex[0][rg] + ex[1][rg];
    #pragma unroll
    for (int off = 1; off < 16; off <<= 1)
        #pragma unroll
        for (int rg = 0; rg < 4; ++rg) sm[rg] += __shfl_xor(sm[rg], off);
    if (mrow == 0)
        #pragma unroll
        for (int rg = 0; rg < 4; ++rg) lsh[wave][quad * 4 + rg] = sm[rg];
    #pragma unroll
    for (int st = 0; st < 2; ++st)
        #pragma unroll
        for (int rg = 0; rg < 4; ++rg)
            psh[(quad * 4 + rg) * 136 + wave * 32 + st * 16 + mrow] = f2bf(ex[st][rg]);
    __syncthreads();

    if (wave == 0 && mrow == 0) {
        #pragma unroll
        for (int rg = 0; rg < 4; ++rg) {
            int m = quad * 4 + rg;
            float l = lsh[0][m] + lsh[1][m] + lsh[2][m] + lsh[3][m];
            stats[blockIdx.x * 16 + m] = make_float2(M[rg], l);
        }
    }

    const short* vbase = vT + (size_t)b * 256 * 512;
    f32x4 o[4];
    #pragma unroll
    for (int i = 0; i < 4; ++i) o[i] = (f32x4){0.f, 0.f, 0.f, 0.f};
    #pragma unroll
    for (int ks = 0; ks < 4; ++ks) {
        bf16x8 pf = *reinterpret_cast<const bf16x8*>(&psh[mrow * 136 + ks * 32 + quad * 8]);
        #pragma unroll
        for (int i = 0; i < 4; ++i) {
            int d0 = (wave * 4 + i) * 16;
            bf16x8 vf = *reinterpret_cast<const bf16x8*>(
                vbase + (size_t)(d0 + mrow) * 512 + sc * 128 + ks * 32 + quad * 8);
            o[i] = __builtin_amdgcn_mfma_f32_16x16x32_bf16(pf, vf, o[i], 0, 0, 0);
        }
    }
    #pragma unroll
    for (int i = 0; i < 4; ++i)
        #pragma unroll
        for (int rg = 0; rg < 4; ++rg)
            po[((size_t)blockIdx.x * 16 + quad * 4 + rg) * 256 + (wave * 4 + i) * 16 + mrow] =
                o[i][rg];
}

// ---------------- k3b: combine 4 chunk partials per row --------------------
__global__ __launch_bounds__(256) void k3b_combine(
    const float* __restrict__ po, const float2* __restrict__ stats,
    float* __restrict__ out)
{
    const int row = blockIdx.x;
    const int qt = row >> 4, m = row & 15;
    const int c = threadIdx.x;
    float2 s0 = stats[(qt * 4 + 0) * 16 + m];
    float2 s1 = stats[(qt * 4 + 1) * 16 + m];
    float2 s2 = stats[(qt * 4 + 2) * 16 + m];
    float2 s3 = stats[(qt * 4 + 3) * 16 + m];
    float M = fmaxf(fmaxf(s0.x, s1.x), fmaxf(s2.x, s3.x));
    float a0 = __expf(s0.x - M), a1 = __expf(s1.x - M);
    float a2 = __expf(s2.x - M), a3 = __expf(s3.x - M);
    float inv = 1.f / (a0 * s0.y + a1 * s1.y + a2 * s2.y + a3 * s3.y);
    float acc = a0 * po[((size_t)(qt * 4 + 0) * 16 + m) * 256 + c]
              + a1 * po[((size_t)(qt * 4 + 1) * 16 + m) * 256 + c]
              + a2 * po[((size_t)(qt * 4 + 2) * 16 + m) * 256 + c]
              + a3 * po[((size_t)(qt * 4 + 3) * 16 + m) * 256 + c];
    out[(size_t)row * 256 + c] = acc * inv;
}

extern "C" void kernel_launch(void* const* d_in, const int* in_sizes, int n_in,
                              void* d_out, int out_size, void* d_ws, size_t ws_size,
                              hipStream_t stream) {
    const float* x    = (const float*)d_in[0];
    const float* r    = (const float*)d_in[1];
    const float* w1   = (const float*)d_in[2];
    const float* b1   = (const float*)d_in[3];
    const float* g1   = (const float*)d_in[4];
    const float* be1  = (const float*)d_in[5];
    const float* m1   = (const float*)d_in[6];
    const float* v1   = (const float*)d_in[7];
    const float* w2   = (const float*)d_in[8];
    const float* b2   = (const float*)d_in[9];
    const float* g2   = (const float*)d_in[10];
    const float* be2  = (const float*)d_in[11];
    const float* m2   = (const float*)d_in[12];
    const float* v2   = (const float*)d_in[13];
    const float* wqkv = (const float*)d_in[14];
    float* out = (float*)d_out;

    // ws layout (bytes):
    //   qbf   [1024*768] bf16  @ 0
    //   vT    [2*256*512] bf16 @ 1,572,864
    //   xbb   [1024*256] bf16  @ 2,097,152
    //   wT    [768*256] bf16   @ 2,621,440
    //   po    [256*16*256] f32 @ 3,014,656
    //   stats [256*16] float2  @ 7,208,960
    char* ws = (char*)d_ws;
    short*  qbf   = (short*)(ws);
    short*  vT    = (short*)(ws + 1572864);
    short*  xbb   = (short*)(ws + 2097152);
    short*  wT    = (short*)(ws + 2621440);
    float*  po    = (float*)(ws + 3014656);
    float2* stats = (float2*)(ws + 7208960);

    k1m_mlp_bias<<<1072, 256, 0, stream>>>(x, r, w1, b1, g1, be1, m1, v1,
                                           w2, b2, g2, be2, m2, v2, wqkv, xbb, wT);
    k2m_qkv<<<192, 256, 0, stream>>>(xbb, wT, qbf, vT);
    k3a_attn<<<256, 256, 0, stream>>>(qbf, vT, po, stats);
    k3b_combine<<<1024, 256, 0, stream>>>(po, stats, out);
}